// Round 2
// baseline (457.071 us; speedup 1.0000x reference)
//
#include <hip/hip_runtime.h>

#define DIM 384
#define NSEG 1024
#define CHUNK 64        // rows per chunk
#define LDA 392         // shorts per LDS A row (384 + 8 pad)
#define WPAD 50         // floats per w-exchange row (2-way bank free)
#define CPB 4           // chunks per persistent block

typedef __attribute__((ext_vector_type(8))) short bf16x8;
typedef __attribute__((ext_vector_type(4))) float f32x4;

static __device__ __forceinline__ short f2bf(float f) {
    union { float f; unsigned u; } v{f};
    unsigned r = (v.u + 0x7FFFu + ((v.u >> 16) & 1u)) >> 16;
    return (short)r;
}

// ---------------- fused prep: weight packing + histogram ----------------
// pack: pb[((mat*24 + T)*12 + ks)*512 + lane*8 + e]
//         = W[T*16 + (lane&15)][ks*32 + (lane>>4)*8 + e]
#define PACK_BLOCKS ((2 * 24 * 12 * 64) / 256)   // 144

__global__ void prep_kernel(const int* __restrict__ ix, int* __restrict__ hist,
                            const float* __restrict__ fw, const float* __restrict__ gw,
                            short* __restrict__ pb, int H) {
    int b = blockIdx.x;
    if (b < PACK_BLOCKS) {
        int idx = b * 256 + threadIdx.x;
        int lane = idx & 63;
        int ks   = (idx >> 6) % 12;
        int T    = ((idx >> 6) / 12) % 24;
        int mat  = idx / (64 * 12 * 24);
        const float* src = mat ? gw : fw;
        int ch = T * 16 + (lane & 15);
        int k0 = ks * 32 + (lane >> 4) * 8;
        short* dst = pb + (size_t)idx * 8;
#pragma unroll
        for (int e = 0; e < 8; e++) dst[e] = f2bf(src[(size_t)ch * DIM + k0 + e]);
    } else {
        int i = (b - PACK_BLOCKS) * 256 + threadIdx.x;
        if (i < H) atomicAdd(&hist[ix[i]], 1);
    }
}

// ---------------- counting sort ----------------

__global__ void scan_kernel(const int* __restrict__ hist, int* __restrict__ seg_start,
                            int* __restrict__ cursor) {
    __shared__ int tmp[NSEG];
    int t = threadIdx.x;
    int v = hist[t];
    tmp[t] = v;
    __syncthreads();
    for (int off = 1; off < NSEG; off <<= 1) {
        int add = (t >= off) ? tmp[t - off] : 0;
        __syncthreads();
        tmp[t] += add;
        __syncthreads();
    }
    int incl = tmp[t];
    seg_start[t] = incl - v;
    cursor[t]    = incl - v;
    if (t == NSEG - 1) seg_start[NSEG] = incl;
}

__global__ void scatter_kernel(const int* __restrict__ ix, int* __restrict__ cursor,
                               int* __restrict__ order, int H) {
    int i = blockIdx.x * blockDim.x + threadIdx.x;
    if (i < H) {
        int p = atomicAdd(&cursor[ix[i]], 1);
        order[p] = i;
    }
}

// ---------------- fused chunk GEMM + segmented softmax reduce (v2) ----------------
// Persistent blocks: 1024 threads (16 waves), CPB chunks of 64 sorted rows each.
// Mat-split: waves 0-7 compute f for ch [48w,48w+48) x all 64 rows (4rt x 3t acc
// = 48 regs); waves 8-15 compute g for the same channels. g-waves exp() their
// result into a 102 KB LDS w-buffer (aliases the A tile, dead after MFMA);
// f-waves read w and reduce num. Epilogue = per-thread run-compression on the
// sorted segment ids -> direct global fp32 atomics (no LDS slot accumulator).
// T14 async staging: next chunk's order/ix/x loads issued during MFMA/epilogue,
// LDS A-write after the w-reads complete (B3).
__global__ __launch_bounds__(1024, 4) void seg_gemm_chunk(
    const float* __restrict__ x, const short* __restrict__ pb,
    const float* __restrict__ f_b, const float* __restrict__ g_b,
    const int* __restrict__ order, const int* __restrict__ ix,
    float* __restrict__ den_acc, float* __restrict__ num_acc, int nchunks) {

    __shared__ char uni[8 * CHUNK * WPAD * 4];   // 102400 B: A (50176 B) ∪ W
    __shared__ int segrow[2][CHUNK];
    __shared__ int norder[CHUNK];

    short* As = (short*)uni;
    float* W  = (float*)uni;                     // W[pair][row][WPAD]

    const int tid  = threadIdx.x;
    const int lane = tid & 63;
    const int wave = tid >> 6;
    const int n = lane & 15, q = lane >> 4;
    const bool isG = wave >= 8;
    const int pair = isG ? wave - 8 : wave;
    const int cb   = pair * 48;

    const int gc0 = blockIdx.x * CPB;
    int mych = nchunks - gc0;
    if (mych <= 0) return;
    if (mych > CPB) mych = CPB;

    float bv[3];
#pragma unroll
    for (int t = 0; t < 3; t++)
        bv[t] = (isG ? g_b : f_b)[cb + t * 16 + n];

    const int r  = tid >> 4;   // 0..63 (16 threads per row)
    const int c6 = tid & 15;

    // ---- prologue: stage chunk gc0 ----
    {
        int gr = order[gc0 * CHUNK + r];
        if (c6 == 0) segrow[0][r] = ix[gr];
        const f32x4* xr = (const f32x4*)(x + (size_t)gr * DIM);
        f32x4 sv[6];
#pragma unroll
        for (int i = 0; i < 6; i++) sv[i] = __builtin_nontemporal_load(xr + c6 + 16 * i);
        short* dst = &As[r * LDA];
#pragma unroll
        for (int i = 0; i < 6; i++) {
            short4 s = { f2bf(sv[i][0]), f2bf(sv[i][1]), f2bf(sv[i][2]), f2bf(sv[i][3]) };
            *(short4*)&dst[(c6 + 16 * i) * 4] = s;
        }
    }
    __syncthreads();

    for (int c = 0; c < mych; c++) {
        const int buf = c & 1;
        const bool hn = (c + 1) < mych;

        // early-issue next chunk's order (latency hidden under MFMA phase)
        int nxt_gr = 0;
        if (wave == 8 && hn) nxt_gr = order[(gc0 + c + 1) * CHUNK + lane];

        f32x4 acc[4][3];
#pragma unroll
        for (int rt = 0; rt < 4; rt++)
#pragma unroll
            for (int t = 0; t < 3; t++) acc[rt][t] = (f32x4){0.f, 0.f, 0.f, 0.f};

        const size_t mb = isG ? 24 : 0;
#pragma unroll
        for (int ks = 0; ks < 12; ks++) {
            bf16x8 a[4];
#pragma unroll
            for (int rt = 0; rt < 4; rt++)
                a[rt] = *(const bf16x8*)&As[(rt * 16 + n) * LDA + ks * 32 + q * 8];
#pragma unroll
            for (int t = 0; t < 3; t++) {
                bf16x8 bf = *(const bf16x8*)(pb + ((mb + pair * 3 + t) * 12 + ks) * 512 + lane * 8);
#pragma unroll
                for (int rt = 0; rt < 4; rt++)
                    acc[rt][t] = __builtin_amdgcn_mfma_f32_16x16x32_bf16(a[rt], bf, acc[rt][t], 0, 0, 0);
            }
        }
        __syncthreads();   // B1: all A reads done; W region (aliases A) free

        int nseg = 0;
        if (wave == 8 && hn) {
            nseg = ix[nxt_gr];          // chained load, issued now, used at B3
            norder[lane] = nxt_gr;
        }

        if (isG) {
            // g: w = exp(clip(gx)), stash to LDS, run-compressed den partials
#pragma unroll
            for (int t = 0; t < 3; t++) {
                int ch = cb + t * 16 + n;
                float rw = 0.f; int cur = -1;
#pragma unroll
                for (int rt = 0; rt < 4; rt++)
#pragma unroll
                    for (int rr = 0; rr < 4; rr++) {
                        int m = rt * 16 + q * 4 + rr;   // ascending
                        int seg = segrow[buf][m];
                        float gx = acc[rt][t][rr] + bv[t];
                        gx = fmaxf(-50.f, fminf(50.f, gx));
                        float w = __expf(gx);
                        W[((size_t)pair * CHUNK + m) * WPAD + t * 16 + n] = w;
                        if (seg != cur) {
                            if (cur >= 0) atomicAdd(&den_acc[(size_t)cur * DIM + ch], rw);
                            cur = seg; rw = 0.f;
                        }
                        rw += w;
                    }
                atomicAdd(&den_acc[(size_t)cur * DIM + ch], rw);
            }
        }
        __syncthreads();   // B2: w-matrix + norder visible

        // T14 stage-issue for next chunk (all threads) — loads fly during reduce
        f32x4 sv[6];
        if (hn) {
            int grn = norder[r];
            const f32x4* xr = (const f32x4*)(x + (size_t)grn * DIM);
#pragma unroll
            for (int i = 0; i < 6; i++) sv[i] = __builtin_nontemporal_load(xr + c6 + 16 * i);
        }

        if (!isG) {
            // f: read w, run-compressed num partials
#pragma unroll
            for (int t = 0; t < 3; t++) {
                int ch = cb + t * 16 + n;
                float rf = 0.f; int cur = -1;
#pragma unroll
                for (int rt = 0; rt < 4; rt++)
#pragma unroll
                    for (int rr = 0; rr < 4; rr++) {
                        int m = rt * 16 + q * 4 + rr;
                        int seg = segrow[buf][m];
                        float w = W[((size_t)pair * CHUNK + m) * WPAD + t * 16 + n];
                        float val = (acc[rt][t][rr] + bv[t]) * w;
                        if (seg != cur) {
                            if (cur >= 0) atomicAdd(&num_acc[(size_t)cur * DIM + ch], rf);
                            cur = seg; rf = 0.f;
                        }
                        rf += val;
                    }
                atomicAdd(&num_acc[(size_t)cur * DIM + ch], rf);
            }
        }
        if (wave == 8 && hn) segrow[buf ^ 1][lane] = nseg;
        __syncthreads();   // B3: w reads done; segrow[next] ready

        if (hn) {
            short* dst = &As[r * LDA];
#pragma unroll
            for (int i = 0; i < 6; i++) {
                short4 s = { f2bf(sv[i][0]), f2bf(sv[i][1]), f2bf(sv[i][2]), f2bf(sv[i][3]) };
                *(short4*)&dst[(c6 + 16 * i) * 4] = s;
            }
        }
        __syncthreads();   // B4: A staged for next chunk
    }
}

// ---------------- small h GEMM: z = (num/den) @ h_w^T + h_b (fp32) ----------------
__global__ __launch_bounds__(256) void hgemm_kernel(
    const float* __restrict__ num, const float* __restrict__ den,
    const float* __restrict__ h_w, const float* __restrict__ h_b,
    float* __restrict__ z) {
    const int m0 = blockIdx.x * 64;
    const int c0 = blockIdx.y * 64;
    const int tid = threadIdx.x;
    const int ty = tid >> 4, tx = tid & 15;
    __shared__ float As[16][64];
    __shared__ float Bs[16][64];
    float acc[4][4];
#pragma unroll
    for (int i = 0; i < 4; i++)
#pragma unroll
        for (int j = 0; j < 4; j++) acc[i][j] = 0.f;

    for (int k0 = 0; k0 < DIM; k0 += 16) {
        __syncthreads();
        {
            int m  = tid >> 2;
            int kq = (tid & 3) << 2;
            size_t idx = (size_t)(m0 + m) * DIM + k0 + kq;
            float4 v = *(const float4*)(num + idx);
            float4 d = *(const float4*)(den + idx);
            v.x /= fmaxf(d.x, 1e-9f); v.y /= fmaxf(d.y, 1e-9f);
            v.z /= fmaxf(d.z, 1e-9f); v.w /= fmaxf(d.w, 1e-9f);
            As[kq + 0][m] = v.x; As[kq + 1][m] = v.y;
            As[kq + 2][m] = v.z; As[kq + 3][m] = v.w;
            float4 w = *(const float4*)(h_w + (size_t)(c0 + m) * DIM + k0 + kq);
            Bs[kq + 0][m] = w.x; Bs[kq + 1][m] = w.y;
            Bs[kq + 2][m] = w.z; Bs[kq + 3][m] = w.w;
        }
        __syncthreads();
#pragma unroll
        for (int kk = 0; kk < 16; kk++) {
            float4 a4 = *(const float4*)&As[kk][ty * 4];
            float4 b4 = *(const float4*)&Bs[kk][tx * 4];
            float a[4] = { a4.x, a4.y, a4.z, a4.w };
            float b[4] = { b4.x, b4.y, b4.z, b4.w };
#pragma unroll
            for (int i = 0; i < 4; i++)
#pragma unroll
                for (int j = 0; j < 4; j++) acc[i][j] += a[i] * b[j];
        }
    }
#pragma unroll
    for (int i = 0; i < 4; i++)
#pragma unroll
        for (int j = 0; j < 4; j++)
            z[(size_t)(m0 + ty * 4 + i) * DIM + c0 + tx * 4 + j] = acc[i][j] + h_b[c0 + tx * 4 + j];
}

// ---------------- gather: out[i] = z[ix[i]] (nt store: don't thrash L2) ----------------
__global__ void gather_kernel(const int* __restrict__ ix, const f32x4* __restrict__ z,
                              f32x4* __restrict__ out, int H) {
    int t = blockIdx.x * blockDim.x + threadIdx.x;
    int total = H * (DIM / 4);
    if (t < total) {
        int i = t / (DIM / 4);
        int qq = t - i * (DIM / 4);
        f32x4 v = z[(size_t)ix[i] * (DIM / 4) + qq];
        __builtin_nontemporal_store(v, out + (size_t)i * (DIM / 4) + qq);
    }
}

extern "C" void kernel_launch(void* const* d_in, const int* in_sizes, int n_in,
                              void* d_out, int out_size, void* d_ws, size_t ws_size,
                              hipStream_t stream) {
    const float* x   = (const float*)d_in[0];
    const int*   ix  = (const int*)d_in[1];
    const float* f_w = (const float*)d_in[2];
    const float* f_b = (const float*)d_in[3];
    const float* g_w = (const float*)d_in[4];
    const float* g_b = (const float*)d_in[5];
    const float* h_w = (const float*)d_in[6];
    const float* h_b = (const float*)d_in[7];
    float* out = (float*)d_out;
    const int H = in_sizes[0] / DIM;
    const int nchunks = H / CHUNK;

    char* w = (char*)d_ws;
    int* hist      = (int*)w;   w += 4096;                     // 1024 ints
    int* seg_start = (int*)w;   w += 8192;                     // 1025 ints (padded)
    int* cursor    = (int*)w;   w += 4096;                     // 1024 ints
    int* order     = (int*)w;   w += (size_t)H * 4;            // H ints
    float* den_acc = (float*)w; w += (size_t)NSEG * DIM * 4;   // zeroed below
    float* num_acc = (float*)w; w += (size_t)NSEG * DIM * 4;   // zeroed below (contiguous)
    float* z       = (float*)w; w += (size_t)NSEG * DIM * 4;
    short* pb      = (short*)w;                                // packed f+g weights

    (void)hipMemsetAsync(hist, 0, NSEG * sizeof(int), stream);
    (void)hipMemsetAsync(den_acc, 0, (size_t)2 * NSEG * DIM * 4, stream);
    prep_kernel<<<PACK_BLOCKS + (H + 255) / 256, 256, 0, stream>>>(ix, hist, f_w, g_w, pb, H);
    scan_kernel<<<1, NSEG, 0, stream>>>(hist, seg_start, cursor);
    scatter_kernel<<<(H + 255) / 256, 256, 0, stream>>>(ix, cursor, order, H);
    seg_gemm_chunk<<<(nchunks + CPB - 1) / CPB, 1024, 0, stream>>>(
        x, pb, f_b, g_b, order, ix, den_acc, num_acc, nchunks);
    hgemm_kernel<<<dim3(NSEG / 64, DIM / 64), 256, 0, stream>>>(num_acc, den_acc,
                                                                h_w, h_b, z);
    gather_kernel<<<(H * (DIM / 4) + 255) / 256, 256, 0, stream>>>(
        ix, (const f32x4*)z, (f32x4*)out, H);
}

// Round 3
// 338.503 us; speedup vs baseline: 1.3503x; 1.3503x over previous
//
#include <hip/hip_runtime.h>

#define DIM 384
#define NSEG 1024
#define CHUNK 64        // rows per block
#define LDA 392         // shorts per LDS A row (384 + 8 pad)
#define MAXLS 16        // LDS segment slots per chunk (64-row sorted window spans ~2-3)

typedef __attribute__((ext_vector_type(8))) short bf16x8;
typedef __attribute__((ext_vector_type(4))) float f32x4;

static __device__ __forceinline__ short f2bf(float f) {
    union { float f; unsigned u; } v{f};
    unsigned r = (v.u + 0x7FFFu + ((v.u >> 16) & 1u)) >> 16;
    return (short)r;
}

// ---------------- fused prep: weight packing + histogram ----------------
// pack: pb[((mat*24 + T)*12 + ks)*512 + lane*8 + e]
//         = W[T*16 + (lane&15)][ks*32 + (lane>>4)*8 + e]
#define PACK_BLOCKS ((2 * 24 * 12 * 64) / 256)   // 144

__global__ void prep_kernel(const int* __restrict__ ix, int* __restrict__ hist,
                            const float* __restrict__ fw, const float* __restrict__ gw,
                            short* __restrict__ pb, int H) {
    int b = blockIdx.x;
    if (b < PACK_BLOCKS) {
        int idx = b * 256 + threadIdx.x;
        int lane = idx & 63;
        int ks   = (idx >> 6) % 12;
        int T    = ((idx >> 6) / 12) % 24;
        int mat  = idx / (64 * 12 * 24);
        const float* src = mat ? gw : fw;
        int ch = T * 16 + (lane & 15);
        int k0 = ks * 32 + (lane >> 4) * 8;
        short* dst = pb + (size_t)idx * 8;
#pragma unroll
        for (int e = 0; e < 8; e++) dst[e] = f2bf(src[(size_t)ch * DIM + k0 + e]);
    } else {
        int i = (b - PACK_BLOCKS) * 256 + threadIdx.x;
        if (i < H) atomicAdd(&hist[ix[i]], 1);
    }
}

// ---------------- counting sort ----------------

__global__ void scan_kernel(const int* __restrict__ hist, int* __restrict__ seg_start,
                            int* __restrict__ cursor) {
    __shared__ int tmp[NSEG];
    int t = threadIdx.x;
    int v = hist[t];
    tmp[t] = v;
    __syncthreads();
    for (int off = 1; off < NSEG; off <<= 1) {
        int add = (t >= off) ? tmp[t - off] : 0;
        __syncthreads();
        tmp[t] += add;
        __syncthreads();
    }
    int incl = tmp[t];
    seg_start[t] = incl - v;
    cursor[t]    = incl - v;
    if (t == NSEG - 1) seg_start[NSEG] = incl;
}

__global__ void scatter_kernel(const int* __restrict__ ix, int* __restrict__ cursor,
                               int* __restrict__ order, int H) {
    int i = blockIdx.x * blockDim.x + threadIdx.x;
    if (i < H) {
        int p = atomicAdd(&cursor[ix[i]], 1);
        order[p] = i;
    }
}

// ---------------- fused chunk GEMM + segmented softmax reduce (v3) ----------------
// Grid = H/64 blocks; block b owns sorted positions [64b, 64b+64).
// 16 waves (1024 thr): wave w -> channels 48*(w&7)..+48 (tiles 3p..3p+2, BOTH
// mats), rows 32*(w>>3)..+32 (row-tiles 2h, 2h+1). acc = 2x3x2 f32x4 = 48
// regs/thread, so a 1024-thread block fits the <=128-reg tier: 4 waves/SIMD
// (2x the v1 residency). B fragments are shared by the two row-half waves
// (L1 serves the second reader) so L2 B-traffic is unchanged vs v1.
// Epilogue: v1's run-compressed 16-slot LDS accumulator (reuses A-tile LDS)
// -> per-block flush to global fp32 atomic partials. No mid-loop global
// atomics (the v2 mistake: 7x HBM traffic).
__global__ __launch_bounds__(1024) void seg_gemm_chunk(
    const float* __restrict__ x, const short* __restrict__ pb,
    const float* __restrict__ f_b, const float* __restrict__ g_b,
    const int* __restrict__ order, const int* __restrict__ ix,
    float* __restrict__ den_acc, float* __restrict__ num_acc) {
    const int chunk0 = blockIdx.x * CHUNK;
    const int tid  = threadIdx.x;
    const int lane = tid & 63;
    const int wave = tid >> 6;
    const int n    = lane & 15;
    const int q    = lane >> 4;
    const int pair = wave & 7;       // channel group
    const int half = wave >> 3;      // row half (0: rows 0-31, 1: rows 32-63)
    const int cb   = pair * 48;

    __shared__ short As[CHUNK * LDA];     // 50176 B; aliased as float acc later
    __shared__ int   segrow[CHUNK];

    // ---- stage 64 rows of x (sorted order) as bf16; record segment ids ----
    {
        int r  = tid >> 4;   // 0..63 (16 threads per row)
        int c6 = tid & 15;
        int gr = order[chunk0 + r];
        if (c6 == 0) segrow[r] = ix[gr];
        const f32x4* xr = (const f32x4*)(x + (size_t)gr * DIM);
        short* dst = &As[r * LDA];
#pragma unroll
        for (int i = 0; i < 6; i++) {
            f32x4 v = __builtin_nontemporal_load(xr + c6 + 16 * i);
            short4 s = { f2bf(v[0]), f2bf(v[1]), f2bf(v[2]), f2bf(v[3]) };
            *(short4*)&dst[(c6 + 16 * i) * 4] = s;
        }
    }
    __syncthreads();

    float fbv[3], gbv[3];
#pragma unroll
    for (int t = 0; t < 3; t++) {
        fbv[t] = f_b[cb + t * 16 + n];
        gbv[t] = g_b[cb + t * 16 + n];
    }

    f32x4 accf[2][3], accg[2][3];
#pragma unroll
    for (int rt = 0; rt < 2; rt++)
#pragma unroll
        for (int t = 0; t < 3; t++) {
            accf[rt][t] = (f32x4){0.f, 0.f, 0.f, 0.f};
            accg[rt][t] = (f32x4){0.f, 0.f, 0.f, 0.f};
        }

#pragma unroll
    for (int ks = 0; ks < 12; ks++) {
        bf16x8 a[2];
#pragma unroll
        for (int rt = 0; rt < 2; rt++)
            a[rt] = *(const bf16x8*)&As[((half * 2 + rt) * 16 + n) * LDA + ks * 32 + q * 8];
#pragma unroll
        for (int t = 0; t < 3; t++) {
            int Tg = pair * 3 + t;
            bf16x8 bfr = *(const bf16x8*)(pb + ((size_t)((0 * 24 + Tg) * 12 + ks)) * 512 + lane * 8);
            bf16x8 bgr = *(const bf16x8*)(pb + ((size_t)((1 * 24 + Tg) * 12 + ks)) * 512 + lane * 8);
#pragma unroll
            for (int rt = 0; rt < 2; rt++) {
                accf[rt][t] = __builtin_amdgcn_mfma_f32_16x16x32_bf16(a[rt], bfr, accf[rt][t], 0, 0, 0);
                accg[rt][t] = __builtin_amdgcn_mfma_f32_16x16x32_bf16(a[rt], bgr, accg[rt][t], 0, 0, 0);
            }
        }
    }

    // ---- epilogue: segmented reduce via 16-slot LDS accumulator ----
    const int s0 = segrow[0];
    __syncthreads();                       // all A reads done; reuse LDS
    float* accs = (float*)As;              // [MAXLS][DIM][2]
    for (int i = tid; i < MAXLS * DIM * 2; i += 1024) accs[i] = 0.f;
    __syncthreads();

#pragma unroll
    for (int t = 0; t < 3; t++) {
        int ch = cb + t * 16 + n;
        float rw = 0.f, rf = 0.f;
        int cur = -1;
#pragma unroll
        for (int rt = 0; rt < 2; rt++) {
#pragma unroll
            for (int r = 0; r < 4; r++) {
                int m  = (half * 2 + rt) * 16 + q * 4 + r;   // ascending in (rt, r)
                int ls = segrow[m] - s0;
                if (ls != cur) {
                    if (cur >= 0) {
                        if (cur < MAXLS) {
                            atomicAdd(&accs[(cur * DIM + ch) * 2 + 0], rw);
                            atomicAdd(&accs[(cur * DIM + ch) * 2 + 1], rf);
                        } else {
                            atomicAdd(&den_acc[(size_t)(s0 + cur) * DIM + ch], rw);
                            atomicAdd(&num_acc[(size_t)(s0 + cur) * DIM + ch], rf);
                        }
                    }
                    cur = ls; rw = 0.f; rf = 0.f;
                }
                float gx = accg[rt][t][r] + gbv[t];
                gx = fmaxf(-50.f, fminf(50.f, gx));
                float w = __expf(gx);
                rw += w;
                rf += (accf[rt][t][r] + fbv[t]) * w;
            }
        }
        if (cur < MAXLS) {
            atomicAdd(&accs[(cur * DIM + ch) * 2 + 0], rw);
            atomicAdd(&accs[(cur * DIM + ch) * 2 + 1], rf);
        } else {
            atomicAdd(&den_acc[(size_t)(s0 + cur) * DIM + ch], rw);
            atomicAdd(&num_acc[(size_t)(s0 + cur) * DIM + ch], rf);
        }
    }
    __syncthreads();

    // ---- flush used LDS slots to global partials ----
    int nls = segrow[CHUNK - 1] - s0 + 1;
    if (nls > MAXLS) nls = MAXLS;
    for (int i = tid; i < nls * DIM; i += 1024) {
        int ls = i / DIM, ch = i - ls * DIM;
        float dw = accs[(ls * DIM + ch) * 2 + 0];
        float dn = accs[(ls * DIM + ch) * 2 + 1];
        if (dw != 0.f || dn != 0.f) {
            atomicAdd(&den_acc[(size_t)(s0 + ls) * DIM + ch], dw);
            atomicAdd(&num_acc[(size_t)(s0 + ls) * DIM + ch], dn);
        }
    }
}

// ---------------- small h GEMM: z = (num/den) @ h_w^T + h_b (fp32) ----------------
__global__ __launch_bounds__(256) void hgemm_kernel(
    const float* __restrict__ num, const float* __restrict__ den,
    const float* __restrict__ h_w, const float* __restrict__ h_b,
    float* __restrict__ z) {
    const int m0 = blockIdx.x * 64;
    const int c0 = blockIdx.y * 64;
    const int tid = threadIdx.x;
    const int ty = tid >> 4, tx = tid & 15;
    __shared__ float As[16][64];
    __shared__ float Bs[16][64];
    float acc[4][4];
#pragma unroll
    for (int i = 0; i < 4; i++)
#pragma unroll
        for (int j = 0; j < 4; j++) acc[i][j] = 0.f;

    for (int k0 = 0; k0 < DIM; k0 += 16) {
        __syncthreads();
        {
            int m  = tid >> 2;
            int kq = (tid & 3) << 2;
            size_t idx = (size_t)(m0 + m) * DIM + k0 + kq;
            float4 v = *(const float4*)(num + idx);
            float4 d = *(const float4*)(den + idx);
            v.x /= fmaxf(d.x, 1e-9f); v.y /= fmaxf(d.y, 1e-9f);
            v.z /= fmaxf(d.z, 1e-9f); v.w /= fmaxf(d.w, 1e-9f);
            As[kq + 0][m] = v.x; As[kq + 1][m] = v.y;
            As[kq + 2][m] = v.z; As[kq + 3][m] = v.w;
            float4 w = *(const float4*)(h_w + (size_t)(c0 + m) * DIM + k0 + kq);
            Bs[kq + 0][m] = w.x; Bs[kq + 1][m] = w.y;
            Bs[kq + 2][m] = w.z; Bs[kq + 3][m] = w.w;
        }
        __syncthreads();
#pragma unroll
        for (int kk = 0; kk < 16; kk++) {
            float4 a4 = *(const float4*)&As[kk][ty * 4];
            float4 b4 = *(const float4*)&Bs[kk][tx * 4];
            float a[4] = { a4.x, a4.y, a4.z, a4.w };
            float b[4] = { b4.x, b4.y, b4.z, b4.w };
#pragma unroll
            for (int i = 0; i < 4; i++)
#pragma unroll
                for (int j = 0; j < 4; j++) acc[i][j] += a[i] * b[j];
        }
    }
#pragma unroll
    for (int i = 0; i < 4; i++)
#pragma unroll
        for (int j = 0; j < 4; j++)
            z[(size_t)(m0 + ty * 4 + i) * DIM + c0 + tx * 4 + j] = acc[i][j] + h_b[c0 + tx * 4 + j];
}

// ---------------- gather: out[i] = z[ix[i]] (nt store: don't thrash L2) ----------------
__global__ void gather_kernel(const int* __restrict__ ix, const f32x4* __restrict__ z,
                              f32x4* __restrict__ out, int H) {
    int t = blockIdx.x * blockDim.x + threadIdx.x;
    int total = H * (DIM / 4);
    if (t < total) {
        int i = t / (DIM / 4);
        int qq = t - i * (DIM / 4);
        f32x4 v = z[(size_t)ix[i] * (DIM / 4) + qq];
        __builtin_nontemporal_store(v, out + (size_t)i * (DIM / 4) + qq);
    }
}

extern "C" void kernel_launch(void* const* d_in, const int* in_sizes, int n_in,
                              void* d_out, int out_size, void* d_ws, size_t ws_size,
                              hipStream_t stream) {
    const float* x   = (const float*)d_in[0];
    const int*   ix  = (const int*)d_in[1];
    const float* f_w = (const float*)d_in[2];
    const float* f_b = (const float*)d_in[3];
    const float* g_w = (const float*)d_in[4];
    const float* g_b = (const float*)d_in[5];
    const float* h_w = (const float*)d_in[6];
    const float* h_b = (const float*)d_in[7];
    float* out = (float*)d_out;
    const int H = in_sizes[0] / DIM;

    char* w = (char*)d_ws;
    int* hist      = (int*)w;   w += 4096;                     // 1024 ints
    int* seg_start = (int*)w;   w += 8192;                     // 1025 ints (padded)
    int* cursor    = (int*)w;   w += 4096;                     // 1024 ints
    int* order     = (int*)w;   w += (size_t)H * 4;            // H ints
    float* den_acc = (float*)w; w += (size_t)NSEG * DIM * 4;   // zeroed below
    float* num_acc = (float*)w; w += (size_t)NSEG * DIM * 4;   // zeroed below (contiguous)
    float* z       = (float*)w; w += (size_t)NSEG * DIM * 4;
    short* pb      = (short*)w;                                // packed f+g weights

    (void)hipMemsetAsync(hist, 0, NSEG * sizeof(int), stream);
    (void)hipMemsetAsync(den_acc, 0, (size_t)2 * NSEG * DIM * 4, stream);
    prep_kernel<<<PACK_BLOCKS + (H + 255) / 256, 256, 0, stream>>>(ix, hist, f_w, g_w, pb, H);
    scan_kernel<<<1, NSEG, 0, stream>>>(hist, seg_start, cursor);
    scatter_kernel<<<(H + 255) / 256, 256, 0, stream>>>(ix, cursor, order, H);
    seg_gemm_chunk<<<H / CHUNK, 1024, 0, stream>>>(x, pb, f_b, g_b, order, ix,
                                                   den_acc, num_acc);
    hgemm_kernel<<<dim3(NSEG / 64, DIM / 64), 256, 0, stream>>>(num_acc, den_acc,
                                                                h_w, h_b, z);
    gather_kernel<<<(H * (DIM / 4) + 255) / 256, 256, 0, stream>>>(
        ix, (const f32x4*)z, (f32x4*)out, H);
}

// Round 4
// 312.585 us; speedup vs baseline: 1.4622x; 1.0829x over previous
//
#include <hip/hip_runtime.h>

#define DIM 384
#define NSEG 1024
#define CHUNK 32        // rows per block
#define LDA 392         // shorts per LDS A row (384 + 8 pad)
#define MAXLS 8         // LDS segment slots per chunk (32-row sorted window spans ~1-2)
#define NHB 16          // histogram blocks

typedef __attribute__((ext_vector_type(8))) short bf16x8;
typedef __attribute__((ext_vector_type(4))) float f32x4;

static __device__ __forceinline__ short f2bf(float f) {
    union { float f; unsigned u; } v{f};
    unsigned r = (v.u + 0x7FFFu + ((v.u >> 16) & 1u)) >> 16;
    return (short)r;
}

// ---------------- fused prep: weight packing + per-block partial histograms ----
// pack: pb[((mat*24 + T)*12 + ks)*512 + lane*8 + e]
//         = W[T*16 + (lane&15)][ks*32 + (lane>>4)*8 + e]
// hist: block-local LDS histogram -> hist_part[hb][seg]  (no global atomics)
#define PACKB ((2 * 24 * 12 * 64) / 1024)   // 36 blocks of 1024

__global__ __launch_bounds__(1024) void prep_kernel(
    const int* __restrict__ ix, int* __restrict__ hist_part,
    const float* __restrict__ fw, const float* __restrict__ gw,
    short* __restrict__ pb, int H) {
    __shared__ int lh[NSEG];
    int b = blockIdx.x;
    int t = threadIdx.x;
    if (b < PACKB) {
        int idx = b * 1024 + t;
        int lane = idx & 63;
        int ks   = (idx >> 6) % 12;
        int T    = ((idx >> 6) / 12) % 24;
        int mat  = idx / (64 * 12 * 24);
        const float* src = mat ? gw : fw;
        int ch = T * 16 + (lane & 15);
        int k0 = ks * 32 + (lane >> 4) * 8;
        short* dst = pb + (size_t)idx * 8;
#pragma unroll
        for (int e = 0; e < 8; e++) dst[e] = f2bf(src[(size_t)ch * DIM + k0 + e]);
    } else {
        int hb = b - PACKB;
        lh[t] = 0;
        __syncthreads();
        int rpb = (H + NHB - 1) / NHB;
        int lo = hb * rpb;
        int hi = lo + rpb; if (hi > H) hi = H;
        for (int i = lo + t; i < hi; i += 1024)
            atomicAdd(&lh[ix[i]], 1);
        __syncthreads();
        hist_part[hb * NSEG + t] = lh[t];
    }
}

// ---------------- scan: sum partial hists + shuffle-based prefix ----------------
__global__ __launch_bounds__(1024) void scan_kernel(
    const int* __restrict__ hist_part, int* __restrict__ seg_start,
    int* __restrict__ cursor) {
    __shared__ int wsum[16];
    int t = threadIdx.x;
    int v = 0;
#pragma unroll
    for (int b = 0; b < NHB; b++) v += hist_part[b * NSEG + t];
    int lane = t & 63, wv = t >> 6;
    int s = v;
#pragma unroll
    for (int off = 1; off < 64; off <<= 1) {
        int u = __shfl_up(s, off, 64);
        if (lane >= off) s += u;
    }
    if (lane == 63) wsum[wv] = s;
    __syncthreads();
    if (wv == 0) {
        int ws = (lane < 16) ? wsum[lane] : 0;
#pragma unroll
        for (int off = 1; off < 16; off <<= 1) {
            int u = __shfl_up(ws, off, 64);
            if (lane >= off) ws += u;
        }
        if (lane < 16) wsum[lane] = ws;
    }
    __syncthreads();
    int incl = s + (wv ? wsum[wv - 1] : 0);
    seg_start[t] = incl - v;
    cursor[t]    = incl - v;
    if (t == NSEG - 1) seg_start[NSEG] = incl;
}

// ---------------- scatter: block-local aggregation (kills atomic contention) ----
// Per block: LDS hist -> one ranged global reserve per touched seg -> place via
// LDS rank. Order within a segment is arbitrary (sums are order-independent).
__global__ __launch_bounds__(1024) void scatter_kernel(
    const int* __restrict__ ix, int* __restrict__ cursor,
    int* __restrict__ order, int H) {
    __shared__ int lbase[NSEG];
    __shared__ int lcur[NSEG];
    int t = threadIdx.x;
    int rpb = (H + gridDim.x - 1) / gridDim.x;
    int lo = blockIdx.x * rpb;
    int hi = lo + rpb; if (hi > H) hi = H;
    lbase[t] = 0;
    __syncthreads();
    for (int i = lo + t; i < hi; i += 1024)
        atomicAdd(&lbase[ix[i]], 1);
    __syncthreads();
    int c = lbase[t];
    int base = (c > 0) ? atomicAdd(&cursor[t], c) : 0;
    __syncthreads();
    lbase[t] = base;
    lcur[t] = 0;
    __syncthreads();
    for (int i = lo + t; i < hi; i += 1024) {
        int sg = ix[i];
        int p = lbase[sg] + atomicAdd(&lcur[sg], 1);
        order[p] = i;
    }
}

// ---------------- fused chunk GEMM + segmented softmax reduce (v4) ----------------
// Grid = H/32 blocks of 512 thr (8 waves); block owns 32 sorted rows x all 768
// output channels. Wave w: channels 48w..48w+48 (tiles 3w..3w+2, BOTH mats) x
// both row-tiles. acc = 2rt x 3t x 2mat f32x4 = 48 AGPR; ~104 combined regs ->
// TWO blocks co-resident per CU, so one block's epilogue overlaps the other's
// stage/MFMA phases (v1/v3 were single-resident: phases fully exposed).
// Epilogue: run-compressed 8-slot LDS accumulator (aliases A) -> global fp32
// atomic partials. No mid-loop global atomics.
__global__ __launch_bounds__(512, 4) void seg_gemm_chunk(
    const float* __restrict__ x, const short* __restrict__ pb,
    const float* __restrict__ f_b, const float* __restrict__ g_b,
    const int* __restrict__ order, const int* __restrict__ ix,
    float* __restrict__ den_acc, float* __restrict__ num_acc) {
    const int chunk0 = blockIdx.x * CHUNK;
    const int tid  = threadIdx.x;
    const int lane = tid & 63;
    const int wave = tid >> 6;
    const int n    = lane & 15;
    const int q    = lane >> 4;
    const int cb   = wave * 48;

    __shared__ short As[CHUNK * LDA];     // 25088 B; aliased as float acc later
    __shared__ int   segrow[CHUNK];

    // ---- stage 32 rows of x (sorted order) as bf16; record segment ids ----
    {
        int r  = tid >> 4;   // 0..31 (16 threads per row)
        int c6 = tid & 15;
        int gr = order[chunk0 + r];
        if (c6 == 0) segrow[r] = ix[gr];
        const f32x4* xr = (const f32x4*)(x + (size_t)gr * DIM);
        short* dst = &As[r * LDA];
#pragma unroll
        for (int i = 0; i < 6; i++) {
            f32x4 v = __builtin_nontemporal_load(xr + c6 + 16 * i);
            short4 s = { f2bf(v[0]), f2bf(v[1]), f2bf(v[2]), f2bf(v[3]) };
            *(short4*)&dst[(c6 + 16 * i) * 4] = s;
        }
    }
    __syncthreads();

    float fbv[3], gbv[3];
#pragma unroll
    for (int t = 0; t < 3; t++) {
        fbv[t] = f_b[cb + t * 16 + n];
        gbv[t] = g_b[cb + t * 16 + n];
    }

    f32x4 accf[2][3], accg[2][3];
#pragma unroll
    for (int rt = 0; rt < 2; rt++)
#pragma unroll
        for (int t = 0; t < 3; t++) {
            accf[rt][t] = (f32x4){0.f, 0.f, 0.f, 0.f};
            accg[rt][t] = (f32x4){0.f, 0.f, 0.f, 0.f};
        }

#pragma unroll
    for (int ks = 0; ks < 12; ks++) {
        bf16x8 a[2];
#pragma unroll
        for (int rt = 0; rt < 2; rt++)
            a[rt] = *(const bf16x8*)&As[(rt * 16 + n) * LDA + ks * 32 + q * 8];
#pragma unroll
        for (int t = 0; t < 3; t++) {
            int Tg = wave * 3 + t;
            bf16x8 bfr = *(const bf16x8*)(pb + ((size_t)((0 * 24 + Tg) * 12 + ks)) * 512 + lane * 8);
            bf16x8 bgr = *(const bf16x8*)(pb + ((size_t)((1 * 24 + Tg) * 12 + ks)) * 512 + lane * 8);
#pragma unroll
            for (int rt = 0; rt < 2; rt++) {
                accf[rt][t] = __builtin_amdgcn_mfma_f32_16x16x32_bf16(a[rt], bfr, accf[rt][t], 0, 0, 0);
                accg[rt][t] = __builtin_amdgcn_mfma_f32_16x16x32_bf16(a[rt], bgr, accg[rt][t], 0, 0, 0);
            }
        }
    }

    // ---- epilogue: segmented reduce via 8-slot LDS accumulator ----
    const int s0 = segrow[0];
    __syncthreads();                       // all A reads done; reuse LDS
    float* accs = (float*)As;              // [MAXLS][DIM][2] = 24576 B <= 25088
    for (int i = tid; i < MAXLS * DIM * 2; i += 512) accs[i] = 0.f;
    __syncthreads();

#pragma unroll
    for (int t = 0; t < 3; t++) {
        int ch = cb + t * 16 + n;
        float rw = 0.f, rf = 0.f;
        int cur = -1;
#pragma unroll
        for (int rt = 0; rt < 2; rt++) {
#pragma unroll
            for (int r = 0; r < 4; r++) {
                int m  = rt * 16 + q * 4 + r;       // ascending in (rt, r)
                int ls = segrow[m] - s0;
                if (ls != cur) {
                    if (cur >= 0) {
                        if (cur < MAXLS) {
                            atomicAdd(&accs[(cur * DIM + ch) * 2 + 0], rw);
                            atomicAdd(&accs[(cur * DIM + ch) * 2 + 1], rf);
                        } else {
                            atomicAdd(&den_acc[(size_t)(s0 + cur) * DIM + ch], rw);
                            atomicAdd(&num_acc[(size_t)(s0 + cur) * DIM + ch], rf);
                        }
                    }
                    cur = ls; rw = 0.f; rf = 0.f;
                }
                float gx = accg[rt][t][r] + gbv[t];
                gx = fmaxf(-50.f, fminf(50.f, gx));
                float w = __expf(gx);
                rw += w;
                rf += (accf[rt][t][r] + fbv[t]) * w;
            }
        }
        if (cur < MAXLS) {
            atomicAdd(&accs[(cur * DIM + ch) * 2 + 0], rw);
            atomicAdd(&accs[(cur * DIM + ch) * 2 + 1], rf);
        } else {
            atomicAdd(&den_acc[(size_t)(s0 + cur) * DIM + ch], rw);
            atomicAdd(&num_acc[(size_t)(s0 + cur) * DIM + ch], rf);
        }
    }
    __syncthreads();

    // ---- flush used LDS slots to global partials ----
    int nls = segrow[CHUNK - 1] - s0 + 1;
    if (nls > MAXLS) nls = MAXLS;
    for (int i = tid; i < nls * DIM; i += 512) {
        int ls = i / DIM, ch = i - ls * DIM;
        float dw = accs[(ls * DIM + ch) * 2 + 0];
        float dn = accs[(ls * DIM + ch) * 2 + 1];
        if (dw != 0.f || dn != 0.f) {
            atomicAdd(&den_acc[(size_t)(s0 + ls) * DIM + ch], dw);
            atomicAdd(&num_acc[(size_t)(s0 + ls) * DIM + ch], dn);
        }
    }
}

// ---------------- small h GEMM: z = (num/den) @ h_w^T + h_b (fp32) ----------------
__global__ __launch_bounds__(256) void hgemm_kernel(
    const float* __restrict__ num, const float* __restrict__ den,
    const float* __restrict__ h_w, const float* __restrict__ h_b,
    float* __restrict__ z) {
    const int m0 = blockIdx.x * 64;
    const int c0 = blockIdx.y * 64;
    const int tid = threadIdx.x;
    const int ty = tid >> 4, tx = tid & 15;
    __shared__ float As[16][64];
    __shared__ float Bs[16][64];
    float acc[4][4];
#pragma unroll
    for (int i = 0; i < 4; i++)
#pragma unroll
        for (int j = 0; j < 4; j++) acc[i][j] = 0.f;

    for (int k0 = 0; k0 < DIM; k0 += 16) {
        __syncthreads();
        {
            int m  = tid >> 2;
            int kq = (tid & 3) << 2;
            size_t idx = (size_t)(m0 + m) * DIM + k0 + kq;
            float4 v = *(const float4*)(num + idx);
            float4 d = *(const float4*)(den + idx);
            v.x /= fmaxf(d.x, 1e-9f); v.y /= fmaxf(d.y, 1e-9f);
            v.z /= fmaxf(d.z, 1e-9f); v.w /= fmaxf(d.w, 1e-9f);
            As[kq + 0][m] = v.x; As[kq + 1][m] = v.y;
            As[kq + 2][m] = v.z; As[kq + 3][m] = v.w;
            float4 w = *(const float4*)(h_w + (size_t)(c0 + m) * DIM + k0 + kq);
            Bs[kq + 0][m] = w.x; Bs[kq + 1][m] = w.y;
            Bs[kq + 2][m] = w.z; Bs[kq + 3][m] = w.w;
        }
        __syncthreads();
#pragma unroll
        for (int kk = 0; kk < 16; kk++) {
            float4 a4 = *(const float4*)&As[kk][ty * 4];
            float4 b4 = *(const float4*)&Bs[kk][tx * 4];
            float a[4] = { a4.x, a4.y, a4.z, a4.w };
            float b[4] = { b4.x, b4.y, b4.z, b4.w };
#pragma unroll
            for (int i = 0; i < 4; i++)
#pragma unroll
                for (int j = 0; j < 4; j++) acc[i][j] += a[i] * b[j];
        }
    }
#pragma unroll
    for (int i = 0; i < 4; i++)
#pragma unroll
        for (int j = 0; j < 4; j++)
            z[(size_t)(m0 + ty * 4 + i) * DIM + c0 + tx * 4 + j] = acc[i][j] + h_b[c0 + tx * 4 + j];
}

// ---------------- gather: out[i] = z[ix[i]] (nt store: don't thrash L2) ----------------
__global__ void gather_kernel(const int* __restrict__ ix, const f32x4* __restrict__ z,
                              f32x4* __restrict__ out, int H) {
    int t = blockIdx.x * blockDim.x + threadIdx.x;
    int total = H * (DIM / 4);
    if (t < total) {
        int i = t / (DIM / 4);
        int qq = t - i * (DIM / 4);
        f32x4 v = z[(size_t)ix[i] * (DIM / 4) + qq];
        __builtin_nontemporal_store(v, out + (size_t)i * (DIM / 4) + qq);
    }
}

extern "C" void kernel_launch(void* const* d_in, const int* in_sizes, int n_in,
                              void* d_out, int out_size, void* d_ws, size_t ws_size,
                              hipStream_t stream) {
    const float* x   = (const float*)d_in[0];
    const int*   ix  = (const int*)d_in[1];
    const float* f_w = (const float*)d_in[2];
    const float* f_b = (const float*)d_in[3];
    const float* g_w = (const float*)d_in[4];
    const float* g_b = (const float*)d_in[5];
    const float* h_w = (const float*)d_in[6];
    const float* h_b = (const float*)d_in[7];
    float* out = (float*)d_out;
    const int H = in_sizes[0] / DIM;

    char* w = (char*)d_ws;
    int* hist_part = (int*)w;   w += NHB * NSEG * 4;           // 64 KB partial hists
    int* seg_start = (int*)w;   w += 8192;                     // 1025 ints (padded)
    int* cursor    = (int*)w;   w += 4096;                     // 1024 ints
    int* order     = (int*)w;   w += (size_t)H * 4;            // H ints
    float* den_acc = (float*)w; w += (size_t)NSEG * DIM * 4;   // zeroed below
    float* num_acc = (float*)w; w += (size_t)NSEG * DIM * 4;   // zeroed below (contiguous)
    float* z       = (float*)w; w += (size_t)NSEG * DIM * 4;
    short* pb      = (short*)w;                                // packed f+g weights

    (void)hipMemsetAsync(den_acc, 0, (size_t)2 * NSEG * DIM * 4, stream);
    prep_kernel<<<PACKB + NHB, 1024, 0, stream>>>(ix, hist_part, f_w, g_w, pb, H);
    scan_kernel<<<1, NSEG, 0, stream>>>(hist_part, seg_start, cursor);
    scatter_kernel<<<NHB, 1024, 0, stream>>>(ix, cursor, order, H);
    seg_gemm_chunk<<<H / CHUNK, 512, 0, stream>>>(x, pb, f_b, g_b, order, ix,
                                                  den_acc, num_acc);
    hgemm_kernel<<<dim3(NSEG / 64, DIM / 64), 256, 0, stream>>>(num_acc, den_acc,
                                                                h_w, h_b, z);
    gather_kernel<<<(H * (DIM / 4) + 255) / 256, 256, 0, stream>>>(
        ix, (const f32x4*)z, (f32x4*)out, H);
}